// Round 8
// baseline (1138.728 us; speedup 1.0000x reference)
//
#include <hip/hip_runtime.h>
#include <stdint.h>

#define N_NODES 100000
#define N_EDGES 1600000
#define EAD 7
#define H 64
#define LAT 32
#define NG 512
#define NC 6

#define C1_NPB 32
#define C2_NPB 32
#define HD_NPB 64
#define F4_PER_ARR (N_NODES * LAT / 4)   // 800000 float4 per output array

static_assert(N_NODES % C1_NPB == 0, "conv1_node grid exact");
static_assert(N_NODES % C2_NPB == 0, "conv2_node grid exact");

// ---------------- Threefry-2x32-20, key = (0, 42)  (jax.random.key(42)) ----
__device__ __forceinline__ void threefry2x32_42(uint32_t& x0, uint32_t& x1) {
    const uint32_t k0 = 0u, k1 = 42u;
    const uint32_t k2 = k0 ^ k1 ^ 0x1BD11BDAu;
    x0 += k0; x1 += k1;
#define TF_ROUND(r) { x0 += x1; x1 = (x1 << (r)) | (x1 >> (32 - (r))); x1 ^= x0; }
    TF_ROUND(13) TF_ROUND(15) TF_ROUND(26) TF_ROUND(6)
    x0 += k1; x1 += k2 + 1u;
    TF_ROUND(17) TF_ROUND(29) TF_ROUND(16) TF_ROUND(24)
    x0 += k2; x1 += k0 + 2u;
    TF_ROUND(13) TF_ROUND(15) TF_ROUND(26) TF_ROUND(6)
    x0 += k0; x1 += k1 + 3u;
    TF_ROUND(17) TF_ROUND(29) TF_ROUND(16) TF_ROUND(24)
    x0 += k1; x1 += k2 + 4u;
    TF_ROUND(13) TF_ROUND(15) TF_ROUND(26) TF_ROUND(6)
    x0 += k2; x1 += k0 + 5u;
#undef TF_ROUND
}

// XLA f32 ErfInv (Giles): matches jax.lax.erf_inv on f32
__device__ __forceinline__ float erfinv_f32(float x) {
    float w = -log1pf(-x * x);
    float p;
    if (w < 5.0f) {
        w = w - 2.5f;
        p = 2.81022636e-08f;
        p = fmaf(p, w, 3.43273939e-07f);
        p = fmaf(p, w, -3.5233877e-06f);
        p = fmaf(p, w, -4.39150654e-06f);
        p = fmaf(p, w, 0.00021858087f);
        p = fmaf(p, w, -0.00125372503f);
        p = fmaf(p, w, -0.00417768164f);
        p = fmaf(p, w, 0.246640727f);
        p = fmaf(p, w, 1.50140941f);
    } else {
        w = sqrtf(w) - 3.0f;
        p = -0.000200214257f;
        p = fmaf(p, w, 0.000100950558f);
        p = fmaf(p, w, 0.00134934322f);
        p = fmaf(p, w, -0.00367342844f);
        p = fmaf(p, w, 0.00573950773f);
        p = fmaf(p, w, -0.0076224613f);
        p = fmaf(p, w, 0.00943887047f);
        p = fmaf(p, w, 1.00167406f);
        p = fmaf(p, w, 2.83297682f);
    }
    return p * x;
}

// ---------------- conv1: scalar edge messages (control) ---------------------
__global__ void conv1_edge(const float* __restrict__ x, const int* __restrict__ src,
                           const int* __restrict__ dst, const float* __restrict__ ea,
                           const float* __restrict__ We1, const float* __restrict__ be1,
                           float* __restrict__ agg1) {
    int e = blockIdx.x * blockDim.x + threadIdx.x;
    if (e >= N_EDGES) return;
    float proj = be1[0];
#pragma unroll
    for (int k = 0; k < EAD; k++) proj = fmaf(ea[e * EAD + k], We1[k], proj);
    float m = x[src[e]] + proj;
    m = m > 0.0f ? m : 0.0f;
    atomicAdd(&agg1[dst[e]], m);
}

// ---------------- conv1: per-node MLP 1 -> 64 -> 64, 32 nodes/block ---------
__global__ void conv1_node(const float* __restrict__ x, const float* __restrict__ agg1,
                           const float* __restrict__ W11, const float* __restrict__ b11,
                           const float* __restrict__ W12, const float* __restrict__ b12,
                           const float* __restrict__ eps1, float* __restrict__ hout) {
    __shared__ float sW12[H * H];
    __shared__ float st[4][H];
    int tid = threadIdx.x;
    for (int i = tid; i < H * H; i += 256) sW12[i] = W12[i];
    int sub = tid >> 6, lane = tid & 63;
    float eps = eps1[0];
    float w11 = W11[lane], bb11 = b11[lane], bb12 = b12[lane];
    __syncthreads();
#pragma unroll
    for (int it = 0; it < C1_NPB / 4; it++) {
        int n = blockIdx.x * C1_NPB + it * 4 + sub;
        float h1 = fmaf(eps, x[n], x[n]) + agg1[n];
        float t = fmaf(h1, w11, bb11);
        st[sub][lane] = t > 0.0f ? t : 0.0f;
        __syncthreads();
        float acc = bb12;
#pragma unroll
        for (int j = 0; j < H; j++) acc = fmaf(st[sub][j], sW12[j * H + lane], acc);
        hout[(size_t)n * H + lane] = acc > 0.0f ? acc : 0.0f;
        __syncthreads();
    }
}

// ---------------- conv2: 64-wide edge messages + atomic scatter (control) ---
__global__ void conv2_edge(const float* __restrict__ h, const int* __restrict__ src,
                           const int* __restrict__ dst, const float* __restrict__ ea,
                           const float* __restrict__ We2, const float* __restrict__ be2,
                           float* __restrict__ agg2) {
    int lane = threadIdx.x & 63;
    int e = (blockIdx.x * blockDim.x + threadIdx.x) >> 6;
    if (e >= N_EDGES) return;
    int s = src[e], d = dst[e];
    float proj = be2[lane];
#pragma unroll
    for (int k = 0; k < EAD; k++) proj = fmaf(ea[e * EAD + k], We2[k * H + lane], proj);
    float m = h[(size_t)s * H + lane] + proj;
    m = m > 0.0f ? m : 0.0f;
    atomicAdd(&agg2[(size_t)d * H + lane], m);
}

// ---------------- conv2: per-node MLP 64 -> 64 -> 64, 32 nodes/block --------
// hout aliases hin (each thread reads its element before writing it)
__global__ void conv2_node(const float* __restrict__ hin, const float* __restrict__ agg2,
                           const float* __restrict__ W21, const float* __restrict__ b21,
                           const float* __restrict__ W22, const float* __restrict__ b22,
                           const float* __restrict__ eps2, float* __restrict__ hout) {
    __shared__ float sW21[H * H], sW22[H * H];
    __shared__ float sh2[4][H], st[4][H];
    int tid = threadIdx.x;
    for (int i = tid; i < H * H; i += 256) { sW21[i] = W21[i]; sW22[i] = W22[i]; }
    int sub = tid >> 6, lane = tid & 63;
    float e = eps2[0];
    float bb21 = b21[lane], bb22 = b22[lane];
    __syncthreads();
#pragma unroll
    for (int it = 0; it < C2_NPB / 4; it++) {
        int n = blockIdx.x * C2_NPB + it * 4 + sub;
        float hv = hin[(size_t)n * H + lane];
        sh2[sub][lane] = fmaf(e, hv, hv) + agg2[(size_t)n * H + lane];
        __syncthreads();
        float acc = bb21;
#pragma unroll
        for (int j = 0; j < H; j++) acc = fmaf(sh2[sub][j], sW21[j * H + lane], acc);
        st[sub][lane] = acc > 0.0f ? acc : 0.0f;
        __syncthreads();
        acc = bb22;
#pragma unroll
        for (int j = 0; j < H; j++) acc = fmaf(st[sub][j], sW22[j * H + lane], acc);
        hout[(size_t)n * H + lane] = acc > 0.0f ? acc : 0.0f;
        __syncthreads();
    }
}

// ---------------- heads: GEMVs + JAX noise + z -> STAGING buffers -----------
// R4-R7 bisect: heads' 2 GB traffic is invariant to atomics/NPB/store width;
// only constant is the d_out destination. This round writes d_ws staging;
// copyout_k below is the isolated d_out-write probe.
__global__ void heads_k(const float* __restrict__ h,
                        const float* __restrict__ Wmu, const float* __restrict__ bmu,
                        const float* __restrict__ Wlv, const float* __restrict__ blv,
                        float* __restrict__ z_out, float* __restrict__ mu_out,
                        float* __restrict__ lv_out) {
    __shared__ float sWmu[H * LAT], sWlv[H * LAT];
    __shared__ float sh[8][H];
    int tid = threadIdx.x;
    for (int i = tid; i < H * LAT; i += 256) { sWmu[i] = Wmu[i]; sWlv[i] = Wlv[i]; }
    int sub = tid >> 5, lane = tid & 31;
    float bbmu = bmu[lane], bblv = blv[lane];
    __syncthreads();
    for (int it = 0; it < HD_NPB / 8; it++) {
        int base = blockIdx.x * HD_NPB + it * 8;
        if (base >= N_NODES) break;
        for (int i = tid; i < 8 * H; i += 256) {
            int nn = base + (i >> 6);
            if (nn < N_NODES) sh[i >> 6][i & 63] = h[(size_t)nn * H + (i & 63)];
        }
        __syncthreads();
        int n = base + sub;
        if (n < N_NODES) {
            float mu = bbmu, lv = bblv;
#pragma unroll
            for (int j = 0; j < H; j++) {
                float hv = sh[sub][j];
                mu = fmaf(hv, sWmu[j * LAT + lane], mu);
                lv = fmaf(hv, sWlv[j * LAT + lane], lv);
            }
            // JAX partitionable threefry: counter (0, j); 32-bit draws XOR-fold
            // the two output words. [verified R4: absmax 0.0156]
            uint32_t j = (uint32_t)(n * LAT + lane);
            uint32_t x0 = 0u, x1 = j;
            threefry2x32_42(x0, x1);
            uint32_t bits = x0 ^ x1;
            float f = __uint_as_float((bits >> 9) | 0x3F800000u) - 1.0f;
            const float lo = -0.99999994f;
            float u = fmaxf(lo, fmaf(f, 2.0f, lo));
            float noise = 1.41421356237309515f * erfinv_f32(u);
            float zv = fmaf(noise, expf(0.5f * lv), mu);
            size_t o = (size_t)n * LAT + lane;
            z_out[o] = zv; mu_out[o] = mu; lv_out[o] = lv;
        }
        __syncthreads();
    }
}

// ---------------- copyout: pure float4 d_ws -> d_out probe ------------------
__global__ void copyout_k(const float4* __restrict__ zs, const float4* __restrict__ ms,
                          const float4* __restrict__ ls, float4* __restrict__ out) {
    int i = blockIdx.x * blockDim.x + threadIdx.x;
    if (i < F4_PER_ARR) {
        out[i] = zs[i];
        out[F4_PER_ARR + i] = ms[i];
        out[2 * F4_PER_ARR + i] = ls[i];
    }
}

// ---------------- pool + logits: float4 gathers of z; batch is SORTED -------
__global__ void pool_logits_k(const float4* __restrict__ z4, const int* __restrict__ batch,
                              const float* __restrict__ Wc, const float* __restrict__ bc,
                              float* __restrict__ out) {
    int g = blockIdx.x;
    int tid = threadIdx.x;
    int sub = tid >> 3, slot = tid & 7;
    __shared__ float4 acc4[32][8];
    __shared__ float emb[LAT];
    int lo = 0, hi = N_NODES;
    while (lo < hi) { int mid = (lo + hi) >> 1; if (batch[mid] < g) lo = mid + 1; else hi = mid; }
    int start = lo;
    hi = N_NODES;
    while (lo < hi) { int mid = (lo + hi) >> 1; if (batch[mid] < g + 1) lo = mid + 1; else hi = mid; }
    int end = lo;
    float4 a = make_float4(0.f, 0.f, 0.f, 0.f);
    for (int n = start + sub; n < end; n += 32) {
        float4 v = z4[(size_t)n * (LAT / 4) + slot];
        a.x += v.x; a.y += v.y; a.z += v.z; a.w += v.w;
    }
    acc4[sub][slot] = a;
    __syncthreads();
    if (tid < 8) {
        float4 s4 = acc4[0][tid];
        for (int k = 1; k < 32; k++) {
            s4.x += acc4[k][tid].x; s4.y += acc4[k][tid].y;
            s4.z += acc4[k][tid].z; s4.w += acc4[k][tid].w;
        }
        float invc = 1.0f / fmaxf((float)(end - start), 1.0f);
        emb[tid * 4 + 0] = s4.x * invc; emb[tid * 4 + 1] = s4.y * invc;
        emb[tid * 4 + 2] = s4.z * invc; emb[tid * 4 + 3] = s4.w * invc;
    }
    __syncthreads();
    if (tid < NC) {
        float r = bc[tid];
#pragma unroll
        for (int l = 0; l < LAT; l++) r = fmaf(emb[l], Wc[l * NC + tid], r);
        out[g * NC + tid] = r;
    }
}

extern "C" void kernel_launch(void* const* d_in, const int* in_sizes, int n_in,
                              void* d_out, int out_size, void* d_ws, size_t ws_size,
                              hipStream_t stream) {
    const float* x     = (const float*)d_in[0];
    const int*   ei    = (const int*)d_in[1];
    const float* ea    = (const float*)d_in[2];
    const int*   batch = (const int*)d_in[3];
    const float* We1   = (const float*)d_in[4];
    const float* be1   = (const float*)d_in[5];
    const float* W11   = (const float*)d_in[6];
    const float* b11   = (const float*)d_in[7];
    const float* W12   = (const float*)d_in[8];
    const float* b12   = (const float*)d_in[9];
    const float* eps1  = (const float*)d_in[10];
    const float* We2   = (const float*)d_in[11];
    const float* be2   = (const float*)d_in[12];
    const float* W21   = (const float*)d_in[13];
    const float* b21   = (const float*)d_in[14];
    const float* W22   = (const float*)d_in[15];
    const float* b22   = (const float*)d_in[16];
    const float* eps2  = (const float*)d_in[17];
    const float* Wmu   = (const float*)d_in[18];
    const float* bmu   = (const float*)d_in[19];
    const float* Wlv   = (const float*)d_in[20];
    const float* blv   = (const float*)d_in[21];
    const float* Wc    = (const float*)d_in[22];
    const float* bc    = (const float*)d_in[23];

    // ws layout: [agg1 N][agg2 N*H] <- zeroed; [hA N*H][lvws N*L]
    // conv2_node writes its output IN PLACE over hA (read-before-write per elem),
    // so agg2 is dead after conv2_node -> reuse as zws/muws staging.
    float* agg1 = (float*)d_ws;
    float* agg2 = agg1 + N_NODES;
    float* hA   = agg2 + (size_t)N_NODES * H;
    float* lvws = hA + (size_t)N_NODES * H;
    float* zws  = agg2;                           // 3.2M floats
    float* muws = agg2 + (size_t)N_NODES * LAT;   // 3.2M floats

    size_t need_bytes = ((size_t)N_NODES + 2 * (size_t)N_NODES * H
                         + (size_t)N_NODES * LAT) * sizeof(float);
    int staged = (ws_size >= need_bytes);

    size_t zero_bytes = ((size_t)N_NODES + (size_t)N_NODES * H) * sizeof(float);
    hipMemsetAsync(d_ws, 0, zero_bytes, stream);

    const int* src = ei;
    const int* dst = ei + N_EDGES;

    float* z_out     = (float*)d_out;
    float* mu_out    = z_out + (size_t)N_NODES * LAT;
    float* lv_out    = mu_out + (size_t)N_NODES * LAT;
    float* logit_out = lv_out + (size_t)N_NODES * LAT;

    float* zdst  = staged ? zws  : z_out;
    float* mudst = staged ? muws : mu_out;
    float* lvdst = staged ? lvws : lv_out;

    conv1_edge<<<(N_EDGES + 255) / 256, 256, 0, stream>>>(x, src, dst, ea, We1, be1, agg1);
    conv1_node<<<N_NODES / C1_NPB, 256, 0, stream>>>(x, agg1, W11, b11, W12, b12, eps1, hA);
    conv2_edge<<<N_EDGES / 4, 256, 0, stream>>>(hA, src, dst, ea, We2, be2, agg2);
    conv2_node<<<N_NODES / C2_NPB, 256, 0, stream>>>(hA, agg2, W21, b21, W22, b22, eps2, hA);
    heads_k<<<(N_NODES + HD_NPB - 1) / HD_NPB, 256, 0, stream>>>(
        hA, Wmu, bmu, Wlv, blv, zdst, mudst, lvdst);
    if (staged)
        copyout_k<<<(F4_PER_ARR + 255) / 256, 256, 0, stream>>>(
            (const float4*)zws, (const float4*)muws, (const float4*)lvws, (float4*)d_out);
    pool_logits_k<<<NG, 256, 0, stream>>>((const float4*)zdst, batch, Wc, bc, logit_out);
}

// Round 9
// 766.738 us; speedup vs baseline: 1.4852x; 1.4852x over previous
//
#include <hip/hip_runtime.h>
#include <stdint.h>

#define N_NODES 100000
#define N_EDGES 1600000
#define EAD 7
#define H 64
#define LAT 32
#define NG 512
#define NC 6

#define C1_NPB 32
#define C2_NPB 32
#define HD_NPB 64
#define NZ (N_NODES * LAT)               // 3.2M elements per output array
#define F4_PER_ARR (NZ / 4)              // 800000 float4 per output array

static_assert(N_NODES % C1_NPB == 0, "conv1_node grid exact");
static_assert(N_NODES % C2_NPB == 0, "conv2_node grid exact");

// ---------------- Threefry-2x32-20, key = (0, 42)  (jax.random.key(42)) ----
__device__ __forceinline__ void threefry2x32_42(uint32_t& x0, uint32_t& x1) {
    const uint32_t k0 = 0u, k1 = 42u;
    const uint32_t k2 = k0 ^ k1 ^ 0x1BD11BDAu;
    x0 += k0; x1 += k1;
#define TF_ROUND(r) { x0 += x1; x1 = (x1 << (r)) | (x1 >> (32 - (r))); x1 ^= x0; }
    TF_ROUND(13) TF_ROUND(15) TF_ROUND(26) TF_ROUND(6)
    x0 += k1; x1 += k2 + 1u;
    TF_ROUND(17) TF_ROUND(29) TF_ROUND(16) TF_ROUND(24)
    x0 += k2; x1 += k0 + 2u;
    TF_ROUND(13) TF_ROUND(15) TF_ROUND(26) TF_ROUND(6)
    x0 += k0; x1 += k1 + 3u;
    TF_ROUND(17) TF_ROUND(29) TF_ROUND(16) TF_ROUND(24)
    x0 += k1; x1 += k2 + 4u;
    TF_ROUND(13) TF_ROUND(15) TF_ROUND(26) TF_ROUND(6)
    x0 += k2; x1 += k0 + 5u;
#undef TF_ROUND
}

// XLA f32 ErfInv (Giles): matches jax.lax.erf_inv on f32
__device__ __forceinline__ float erfinv_f32(float x) {
    float w = -log1pf(-x * x);
    float p;
    if (w < 5.0f) {
        w = w - 2.5f;
        p = 2.81022636e-08f;
        p = fmaf(p, w, 3.43273939e-07f);
        p = fmaf(p, w, -3.5233877e-06f);
        p = fmaf(p, w, -4.39150654e-06f);
        p = fmaf(p, w, 0.00021858087f);
        p = fmaf(p, w, -0.00125372503f);
        p = fmaf(p, w, -0.00417768164f);
        p = fmaf(p, w, 0.246640727f);
        p = fmaf(p, w, 1.50140941f);
    } else {
        w = sqrtf(w) - 3.0f;
        p = -0.000200214257f;
        p = fmaf(p, w, 0.000100950558f);
        p = fmaf(p, w, 0.00134934322f);
        p = fmaf(p, w, -0.00367342844f);
        p = fmaf(p, w, 0.00573950773f);
        p = fmaf(p, w, -0.0076224613f);
        p = fmaf(p, w, 0.00943887047f);
        p = fmaf(p, w, 1.00167406f);
        p = fmaf(p, w, 2.83297682f);
    }
    return p * x;
}

// ---------------- conv1: scalar edge messages (control) ---------------------
__global__ void conv1_edge(const float* __restrict__ x, const int* __restrict__ src,
                           const int* __restrict__ dst, const float* __restrict__ ea,
                           const float* __restrict__ We1, const float* __restrict__ be1,
                           float* __restrict__ agg1) {
    int e = blockIdx.x * blockDim.x + threadIdx.x;
    if (e >= N_EDGES) return;
    float proj = be1[0];
#pragma unroll
    for (int k = 0; k < EAD; k++) proj = fmaf(ea[e * EAD + k], We1[k], proj);
    float m = x[src[e]] + proj;
    m = m > 0.0f ? m : 0.0f;
    atomicAdd(&agg1[dst[e]], m);
}

// ---------------- conv1: per-node MLP 1 -> 64 -> 64, 32 nodes/block ---------
__global__ void conv1_node(const float* __restrict__ x, const float* __restrict__ agg1,
                           const float* __restrict__ W11, const float* __restrict__ b11,
                           const float* __restrict__ W12, const float* __restrict__ b12,
                           const float* __restrict__ eps1, float* __restrict__ hout) {
    __shared__ float sW12[H * H];
    __shared__ float st[4][H];
    int tid = threadIdx.x;
    for (int i = tid; i < H * H; i += 256) sW12[i] = W12[i];
    int sub = tid >> 6, lane = tid & 63;
    float eps = eps1[0];
    float w11 = W11[lane], bb11 = b11[lane], bb12 = b12[lane];
    __syncthreads();
#pragma unroll
    for (int it = 0; it < C1_NPB / 4; it++) {
        int n = blockIdx.x * C1_NPB + it * 4 + sub;
        float h1 = fmaf(eps, x[n], x[n]) + agg1[n];
        float t = fmaf(h1, w11, bb11);
        st[sub][lane] = t > 0.0f ? t : 0.0f;
        __syncthreads();
        float acc = bb12;
#pragma unroll
        for (int j = 0; j < H; j++) acc = fmaf(st[sub][j], sW12[j * H + lane], acc);
        hout[(size_t)n * H + lane] = acc > 0.0f ? acc : 0.0f;
        __syncthreads();
    }
}

// ---------------- conv2: 64-wide edge messages + atomic scatter (control) ---
__global__ void conv2_edge(const float* __restrict__ h, const int* __restrict__ src,
                           const int* __restrict__ dst, const float* __restrict__ ea,
                           const float* __restrict__ We2, const float* __restrict__ be2,
                           float* __restrict__ agg2) {
    int lane = threadIdx.x & 63;
    int e = (blockIdx.x * blockDim.x + threadIdx.x) >> 6;
    if (e >= N_EDGES) return;
    int s = src[e], d = dst[e];
    float proj = be2[lane];
#pragma unroll
    for (int k = 0; k < EAD; k++) proj = fmaf(ea[e * EAD + k], We2[k * H + lane], proj);
    float m = h[(size_t)s * H + lane] + proj;
    m = m > 0.0f ? m : 0.0f;
    atomicAdd(&agg2[(size_t)d * H + lane], m);
}

// ---------------- conv2: per-node MLP 64 -> 64 -> 64, in-place over hA ------
__global__ void conv2_node(const float* __restrict__ hin, const float* __restrict__ agg2,
                           const float* __restrict__ W21, const float* __restrict__ b21,
                           const float* __restrict__ W22, const float* __restrict__ b22,
                           const float* __restrict__ eps2, float* __restrict__ hout) {
    __shared__ float sW21[H * H], sW22[H * H];
    __shared__ float sh2[4][H], st[4][H];
    int tid = threadIdx.x;
    for (int i = tid; i < H * H; i += 256) { sW21[i] = W21[i]; sW22[i] = W22[i]; }
    int sub = tid >> 6, lane = tid & 63;
    float e = eps2[0];
    float bb21 = b21[lane], bb22 = b22[lane];
    __syncthreads();
#pragma unroll
    for (int it = 0; it < C2_NPB / 4; it++) {
        int n = blockIdx.x * C2_NPB + it * 4 + sub;
        float hv = hin[(size_t)n * H + lane];
        sh2[sub][lane] = fmaf(e, hv, hv) + agg2[(size_t)n * H + lane];
        __syncthreads();
        float acc = bb21;
#pragma unroll
        for (int j = 0; j < H; j++) acc = fmaf(sh2[sub][j], sW21[j * H + lane], acc);
        st[sub][lane] = acc > 0.0f ? acc : 0.0f;
        __syncthreads();
        acc = bb22;
#pragma unroll
        for (int j = 0; j < H; j++) acc = fmaf(st[sub][j], sW22[j * H + lane], acc);
        hout[(size_t)n * H + lane] = acc > 0.0f ? acc : 0.0f;
        __syncthreads();
    }
}

// ---------------- heads part 1: mu/logvar GEMVs -> d_ws staging -------------
__global__ void heads_ml(const float* __restrict__ h,
                         const float* __restrict__ Wmu, const float* __restrict__ bmu,
                         const float* __restrict__ Wlv, const float* __restrict__ blv,
                         float* __restrict__ muws, float* __restrict__ lvws) {
    __shared__ float sWmu[H * LAT], sWlv[H * LAT];
    __shared__ float sh[8][H];
    int tid = threadIdx.x;
    for (int i = tid; i < H * LAT; i += 256) { sWmu[i] = Wmu[i]; sWlv[i] = Wlv[i]; }
    int sub = tid >> 5, lane = tid & 31;
    float bbmu = bmu[lane], bblv = blv[lane];
    __syncthreads();
    for (int it = 0; it < HD_NPB / 8; it++) {
        int base = blockIdx.x * HD_NPB + it * 8;
        if (base >= N_NODES) break;
        for (int i = tid; i < 8 * H; i += 256) {
            int nn = base + (i >> 6);
            if (nn < N_NODES) sh[i >> 6][i & 63] = h[(size_t)nn * H + (i & 63)];
        }
        __syncthreads();
        int n = base + sub;
        if (n < N_NODES) {
            float mu = bbmu, lv = bblv;
#pragma unroll
            for (int j = 0; j < H; j++) {
                float hv = sh[sub][j];
                mu = fmaf(hv, sWmu[j * LAT + lane], mu);
                lv = fmaf(hv, sWlv[j * LAT + lane], lv);
            }
            size_t o = (size_t)n * LAT + lane;
            muws[o] = mu; lvws[o] = lv;
        }
        __syncthreads();
    }
}

// ---------------- heads part 2: JAX noise + z -> d_ws staging ---------------
// JAX partitionable threefry: counter (0, j); 32-bit draws XOR-fold the two
// output words. [verified R4: absmax 0.0156]
__global__ void heads_z(const float* __restrict__ muws, const float* __restrict__ lvws,
                        float* __restrict__ zws) {
    int i = blockIdx.x * blockDim.x + threadIdx.x;
    if (i >= NZ) return;
    float mu = muws[i], lv = lvws[i];
    uint32_t x0 = 0u, x1 = (uint32_t)i;
    threefry2x32_42(x0, x1);
    uint32_t bits = x0 ^ x1;
    float f = __uint_as_float((bits >> 9) | 0x3F800000u) - 1.0f;
    const float lo = -0.99999994f;
    float u = fmaxf(lo, fmaf(f, 2.0f, lo));
    float noise = 1.41421356237309515f * erfinv_f32(u);
    zws[i] = fmaf(noise, expf(0.5f * lv), mu);
}

// ---------------- copyout: pure float4 d_ws -> d_out probe ------------------
__global__ void copyout_k(const float4* __restrict__ zs, const float4* __restrict__ ms,
                          const float4* __restrict__ ls, float4* __restrict__ out) {
    int i = blockIdx.x * blockDim.x + threadIdx.x;
    if (i < F4_PER_ARR) {
        out[i] = zs[i];
        out[F4_PER_ARR + i] = ms[i];
        out[2 * F4_PER_ARR + i] = ls[i];
    }
}

// ---------------- pool + logits: float4 gathers of staged z; batch SORTED ---
__global__ void pool_logits_k(const float4* __restrict__ z4, const int* __restrict__ batch,
                              const float* __restrict__ Wc, const float* __restrict__ bc,
                              float* __restrict__ out) {
    int g = blockIdx.x;
    int tid = threadIdx.x;
    int sub = tid >> 3, slot = tid & 7;
    __shared__ float4 acc4[32][8];
    __shared__ float emb[LAT];
    int lo = 0, hi = N_NODES;
    while (lo < hi) { int mid = (lo + hi) >> 1; if (batch[mid] < g) lo = mid + 1; else hi = mid; }
    int start = lo;
    hi = N_NODES;
    while (lo < hi) { int mid = (lo + hi) >> 1; if (batch[mid] < g + 1) lo = mid + 1; else hi = mid; }
    int end = lo;
    float4 a = make_float4(0.f, 0.f, 0.f, 0.f);
    for (int n = start + sub; n < end; n += 32) {
        float4 v = z4[(size_t)n * (LAT / 4) + slot];
        a.x += v.x; a.y += v.y; a.z += v.z; a.w += v.w;
    }
    acc4[sub][slot] = a;
    __syncthreads();
    if (tid < 8) {
        float4 s4 = acc4[0][tid];
        for (int k = 1; k < 32; k++) {
            s4.x += acc4[k][tid].x; s4.y += acc4[k][tid].y;
            s4.z += acc4[k][tid].z; s4.w += acc4[k][tid].w;
        }
        float invc = 1.0f / fmaxf((float)(end - start), 1.0f);
        emb[tid * 4 + 0] = s4.x * invc; emb[tid * 4 + 1] = s4.y * invc;
        emb[tid * 4 + 2] = s4.z * invc; emb[tid * 4 + 3] = s4.w * invc;
    }
    __syncthreads();
    if (tid < NC) {
        float r = bc[tid];
#pragma unroll
        for (int l = 0; l < LAT; l++) r = fmaf(emb[l], Wc[l * NC + tid], r);
        out[g * NC + tid] = r;
    }
}

extern "C" void kernel_launch(void* const* d_in, const int* in_sizes, int n_in,
                              void* d_out, int out_size, void* d_ws, size_t ws_size,
                              hipStream_t stream) {
    const float* x     = (const float*)d_in[0];
    const int*   ei    = (const int*)d_in[1];
    const float* ea    = (const float*)d_in[2];
    const int*   batch = (const int*)d_in[3];
    const float* We1   = (const float*)d_in[4];
    const float* be1   = (const float*)d_in[5];
    const float* W11   = (const float*)d_in[6];
    const float* b11   = (const float*)d_in[7];
    const float* W12   = (const float*)d_in[8];
    const float* b12   = (const float*)d_in[9];
    const float* eps1  = (const float*)d_in[10];
    const float* We2   = (const float*)d_in[11];
    const float* be2   = (const float*)d_in[12];
    const float* W21   = (const float*)d_in[13];
    const float* b21   = (const float*)d_in[14];
    const float* W22   = (const float*)d_in[15];
    const float* b22   = (const float*)d_in[16];
    const float* eps2  = (const float*)d_in[17];
    const float* Wmu   = (const float*)d_in[18];
    const float* bmu   = (const float*)d_in[19];
    const float* Wlv   = (const float*)d_in[20];
    const float* blv   = (const float*)d_in[21];
    const float* Wc    = (const float*)d_in[22];
    const float* bc    = (const float*)d_in[23];

    // ws layout (floats), total 12.9M = 51.6 MB — proven budget (R4 passed):
    //   [agg1 0.1M][agg2 6.4M][hA 6.4M]
    // lifetimes: agg2 dead after conv2_node (conv2_node writes IN PLACE to hA)
    //   -> reuse agg2 as muws(3.2M)+lvws(3.2M); hA dead after heads_ml
    //   -> reuse hA prefix as zws(3.2M).
    float* agg1 = (float*)d_ws;
    float* agg2 = agg1 + N_NODES;
    float* hA   = agg2 + (size_t)N_NODES * H;
    float* muws = agg2;
    float* lvws = agg2 + (size_t)NZ;
    float* zws  = hA;

    size_t zero_bytes = ((size_t)N_NODES + (size_t)N_NODES * H) * sizeof(float);
    hipMemsetAsync(d_ws, 0, zero_bytes, stream);

    const int* src = ei;
    const int* dst = ei + N_EDGES;

    conv1_edge<<<(N_EDGES + 255) / 256, 256, 0, stream>>>(x, src, dst, ea, We1, be1, agg1);
    conv1_node<<<N_NODES / C1_NPB, 256, 0, stream>>>(x, agg1, W11, b11, W12, b12, eps1, hA);
    conv2_edge<<<N_EDGES / 4, 256, 0, stream>>>(hA, src, dst, ea, We2, be2, agg2);
    conv2_node<<<N_NODES / C2_NPB, 256, 0, stream>>>(hA, agg2, W21, b21, W22, b22, eps2, hA);
    heads_ml<<<(N_NODES + HD_NPB - 1) / HD_NPB, 256, 0, stream>>>(
        hA, Wmu, bmu, Wlv, blv, muws, lvws);
    heads_z<<<(NZ + 255) / 256, 256, 0, stream>>>(muws, lvws, zws);
    copyout_k<<<(F4_PER_ARR + 255) / 256, 256, 0, stream>>>(
        (const float4*)zws, (const float4*)muws, (const float4*)lvws, (float4*)d_out);
    pool_logits_k<<<NG, 256, 0, stream>>>((const float4*)zws, batch, Wc, bc,
                                          (float*)d_out + 3 * (size_t)NZ);
}